// Round 1
// baseline (649.612 us; speedup 1.0000x reference)
//
#include <hip/hip_runtime.h>
#include <hip/hip_bf16.h>

#define HH 50
#define TT 1024
#define BT 16            // batch tile per block (MFMA M)
#define NB (2048 / BT)   // 128 blocks
#define CHUNK 256        // x staging chunk (timesteps)
#define XST 260          // x LDS row stride (floats), breaks bank alias
#define HST 72           // h LDS row stride (bf16 elems), breaks bank alias

typedef __bf16 bf16x8 __attribute__((ext_vector_type(8)));
typedef float f32x4 __attribute__((ext_vector_type(4)));

union BF8 { bf16x8 v; unsigned short u[8]; };

__device__ __forceinline__ unsigned short f2bf(float f) {
    unsigned int u = __builtin_bit_cast(unsigned int, f);
    u += 0x7fffu + ((u >> 16) & 1u);   // RNE
    return (unsigned short)(u >> 16);
}
__device__ __forceinline__ float rcp_f(float x) { return __builtin_amdgcn_rcpf(x); }
__device__ __forceinline__ float sigm(float x) {
    return rcp_f(1.0f + __expf(-x));                      // graceful at |x| large
}
__device__ __forceinline__ float tanh_f(float x) {
    return __builtin_fmaf(-2.0f, rcp_f(1.0f + __expf(2.0f * x)), 1.0f);
}

__global__ __launch_bounds__(256) void lstm_mfma_kernel(
    const float* __restrict__ x,
    const float* __restrict__ wih1, const float* __restrict__ whh1,
    const float* __restrict__ bih1, const float* __restrict__ bhh1,
    const float* __restrict__ wih2,
    const float* __restrict__ bih2, const float* __restrict__ bhh2,
    const float* __restrict__ fcw,  const float* __restrict__ fcb,
    float* __restrict__ out)
{
    __shared__ float xs[BT * XST];                 // 16.6 KB
    __shared__ unsigned short hb[2][BT * HST];     // 4.6 KB  (bf16 bits)
    __shared__ float h2s[BT * 52];                 // 3.3 KB

    const int tid  = threadIdx.x;
    const int wv   = tid >> 6;        // wave 0..3 = j-block
    const int lane = tid & 63;
    const int l16  = lane & 15;
    const int quad = lane >> 4;
    const int j    = wv * 16 + l16;   // padded gate sub-index 0..63
    const bool jv  = (j < HH);
    const int b0   = blockIdx.x * BT;

    // ---- persistent per-lane weights: Whh B-frags (bf16), Wih column, bias ----
    BF8 bw[4][2];
    float wihS[4], biasS[4];
    #pragma unroll
    for (int t4 = 0; t4 < 4; ++t4) {
        const int row = t4 * HH + j;
        #pragma unroll
        for (int kk = 0; kk < 2; ++kk)
            #pragma unroll
            for (int e = 0; e < 8; ++e) {
                const int k = kk * 32 + quad * 8 + e;
                const float v = (jv && k < HH) ? whh1[row * HH + k] : 0.0f;
                bw[t4][kk].u[e] = f2bf(v);
            }
        wihS[t4]  = jv ? wih1[row] : 0.0f;
        biasS[t4] = jv ? (bih1[row] + bhh1[row]) : 0.0f;
    }

    // zero initial h buffer
    for (int i = tid; i < BT * HST; i += 256) hb[0][i] = 0;

    float c0 = 0.f, c1 = 0.f, c2 = 0.f, c3 = 0.f;
    unsigned short* cur = hb[0];
    unsigned short* nxt = hb[1];

    for (int t = 0; t < TT; ++t) {
        if ((t & (CHUNK - 1)) == 0) {
            // stage next x chunk (uniform branch; prev chunk consumed before last barrier)
            for (int i = tid; i < BT * (CHUNK / 4); i += 256) {
                const int r = i >> 6, c4 = i & 63;
                const float4 xv = ((const float4*)x)[((b0 + r) * TT + t) / 4 + c4];
                *(float4*)&xs[r * XST + c4 * 4] = xv;
            }
            __syncthreads();   // also covers hb[0] zeroing at t==0
        }
        const int tc = t & (CHUNK - 1);

        // A-frags for h_t  (A[m=lane&15][k=quad*8+e], K-halves kk=0,1)
        const bf16x8 a0 = *(const bf16x8*)&cur[l16 * HST + quad * 8];
        const bf16x8 a1 = *(const bf16x8*)&cur[l16 * HST + 32 + quad * 8];

        const float xv0 = xs[(quad * 4 + 0) * XST + tc];
        const float xv1 = xs[(quad * 4 + 1) * XST + tc];
        const float xv2 = xs[(quad * 4 + 2) * XST + tc];
        const float xv3 = xs[(quad * 4 + 3) * XST + tc];

        f32x4 acc[4];
        #pragma unroll
        for (int t4 = 0; t4 < 4; ++t4) {
            acc[t4][0] = __builtin_fmaf(xv0, wihS[t4], biasS[t4]);
            acc[t4][1] = __builtin_fmaf(xv1, wihS[t4], biasS[t4]);
            acc[t4][2] = __builtin_fmaf(xv2, wihS[t4], biasS[t4]);
            acc[t4][3] = __builtin_fmaf(xv3, wihS[t4], biasS[t4]);
        }
        #pragma unroll
        for (int t4 = 0; t4 < 4; ++t4) {
            acc[t4] = __builtin_amdgcn_mfma_f32_16x16x32_bf16(a0, bw[t4][0].v, acc[t4], 0, 0, 0);
            acc[t4] = __builtin_amdgcn_mfma_f32_16x16x32_bf16(a1, bw[t4][1].v, acc[t4], 0, 0, 0);
        }

        // in-register gate math: lane holds i,f,g,o for (b=quad*4+r, j)
        {
            const float ig = sigm(acc[0][0]), fg = sigm(acc[1][0]);
            const float gg = tanh_f(acc[2][0]), og = sigm(acc[3][0]);
            c0 = __builtin_fmaf(fg, c0, ig * gg);
            nxt[(quad * 4 + 0) * HST + j] = f2bf(og * tanh_f(c0));
        }
        {
            const float ig = sigm(acc[0][1]), fg = sigm(acc[1][1]);
            const float gg = tanh_f(acc[2][1]), og = sigm(acc[3][1]);
            c1 = __builtin_fmaf(fg, c1, ig * gg);
            nxt[(quad * 4 + 1) * HST + j] = f2bf(og * tanh_f(c1));
        }
        {
            const float ig = sigm(acc[0][2]), fg = sigm(acc[1][2]);
            const float gg = tanh_f(acc[2][2]), og = sigm(acc[3][2]);
            c2 = __builtin_fmaf(fg, c2, ig * gg);
            nxt[(quad * 4 + 2) * HST + j] = f2bf(og * tanh_f(c2));
        }
        {
            const float ig = sigm(acc[0][3]), fg = sigm(acc[1][3]);
            const float gg = tanh_f(acc[2][3]), og = sigm(acc[3][3]);
            c3 = __builtin_fmaf(fg, c3, ig * gg);
            nxt[(quad * 4 + 3) * HST + j] = f2bf(og * tanh_f(c3));
        }

        unsigned short* tmp = cur; cur = nxt; nxt = tmp;
        __syncthreads();
    }

    // ---- LSTM2: one cell step from zero state, input = h1 (in `cur`) ----
    BF8 bw2[4][2];
    float bias2S[4];
    #pragma unroll
    for (int t4 = 0; t4 < 4; ++t4) {
        const int row = t4 * HH + j;
        #pragma unroll
        for (int kk = 0; kk < 2; ++kk)
            #pragma unroll
            for (int e = 0; e < 8; ++e) {
                const int k = kk * 32 + quad * 8 + e;
                const float v = (jv && k < HH) ? wih2[row * HH + k] : 0.0f;
                bw2[t4][kk].u[e] = f2bf(v);
            }
        bias2S[t4] = jv ? (bih2[row] + bhh2[row]) : 0.0f;
    }
    const bf16x8 a0 = *(const bf16x8*)&cur[l16 * HST + quad * 8];
    const bf16x8 a1 = *(const bf16x8*)&cur[l16 * HST + 32 + quad * 8];
    f32x4 acc2[4];
    #pragma unroll
    for (int t4 = 0; t4 < 4; ++t4) {
        acc2[t4][0] = bias2S[t4]; acc2[t4][1] = bias2S[t4];
        acc2[t4][2] = bias2S[t4]; acc2[t4][3] = bias2S[t4];
    }
    #pragma unroll
    for (int t4 = 0; t4 < 4; ++t4) {
        acc2[t4] = __builtin_amdgcn_mfma_f32_16x16x32_bf16(a0, bw2[t4][0].v, acc2[t4], 0, 0, 0);
        acc2[t4] = __builtin_amdgcn_mfma_f32_16x16x32_bf16(a1, bw2[t4][1].v, acc2[t4], 0, 0, 0);
    }
    #pragma unroll
    for (int r = 0; r < 4; ++r) {
        const float ig = sigm(acc2[0][r]);
        const float gg = tanh_f(acc2[2][r]);
        const float og = sigm(acc2[3][r]);
        const float cc = ig * gg;           // f*c0 term vanishes (c0 = 0)
        const float h2 = og * tanh_f(cc);
        if (jv) h2s[(quad * 4 + r) * 52 + j] = h2;
    }
    __syncthreads();

    // ---- FC: out[b] = h2[b] . fcW + fcb ----
    const int b = tid >> 4, l = tid & 15;
    float p = 0.f;
    for (int jj = l; jj < HH; jj += 16)
        p = __builtin_fmaf(h2s[b * 52 + jj], fcw[jj], p);
    #pragma unroll
    for (int off = 8; off > 0; off >>= 1) p += __shfl_xor(p, off, 16);
    if (l == 0) out[b0 + b] = p + fcb[0];
}

extern "C" void kernel_launch(void* const* d_in, const int* in_sizes, int n_in,
                              void* d_out, int out_size, void* d_ws, size_t ws_size,
                              hipStream_t stream) {
    lstm_mfma_kernel<<<NB, 256, 0, stream>>>(
        (const float*)d_in[0],                      // x
        (const float*)d_in[1], (const float*)d_in[2],  // lstm1 Wih, Whh
        (const float*)d_in[3], (const float*)d_in[4],  // lstm1 bih, bhh
        (const float*)d_in[5],                      // lstm2 Wih
        (const float*)d_in[7], (const float*)d_in[8],  // lstm2 bih, bhh
        (const float*)d_in[9], (const float*)d_in[10], // fc W, b
        (float*)d_out);
}